// Round 8
// baseline (37073.923 us; speedup 1.0000x reference)
//
#include <hip/hip_runtime.h>

#define T_LEN   2048
#define CHUNK   16
#define NCHUNK  (T_LEN / CHUNK)   // 128
#define NTHREADS 512              // 8 waves

// Barrier-free chunked GRU. Block b = batch row b. 8 waves:
//   waves 0-3 ("R"): layer l = wid. Lane c owns W_hh rows {c,64+c,128+c}
//     (192 f32 in regs). Runs CHUNK recurrence steps privately per phase:
//     h broadcast through wave-local LDS history (no cross-wave deps),
//     gate combine in-lane (lane c's 3 dots ARE gate c's hr/hz/hn).
//   waves 4-6: gx projections for layers 1-3 (lane c owns W_ih rows
//     {c,64+c,128+c}); wave 7: layer-0 gx from x (12 weights).
// Phase p: R-wave l does chunk k=p-2l; G-wave for layer j does chunk
// p-2j+1 (consumed next phase; its h input was produced last phase).
// ONE __syncthreads per phase (134 total) instead of 2 per step (4102).
//
// Register budget: 8-wave WG + waves_per_eu(2,2) is exactly satisfiable by
// ONE workgroup (2 waves/SIMD) -> unified budget 512/2 = 256 regs/thread.
// (7- and 14-wave WGs forced multi-WG assumptions -> 112/64 caps, r1-r7.)
// Demand = 192 weights + ~40 temps = ~232 <= 256. LDS 130KB pins 1 WG/CU.
__global__ __launch_bounds__(NTHREADS)
__attribute__((amdgpu_waves_per_eu(2, 2)))
void gru_fused(const float* __restrict__ x,
               const float* __restrict__ w_ih0,
               const float* __restrict__ w_ih_rest,
               const float* __restrict__ w_hh,
               const float* __restrict__ b_ih,
               const float* __restrict__ b_hh,
               const float* __restrict__ fc_w,
               const float* __restrict__ fc_b,
               float* __restrict__ out)
{
    __shared__ __align__(16) float hist[4][2][CHUNK][64];    // 32 KB  h history
    __shared__ __align__(16) float gxb [4][2][CHUNK][192];   // 98 KB  gx (bias folded)

    const int tid = threadIdx.x;
    const int b   = blockIdx.x;
    const int wid = tid >> 6;
    const int c   = tid & 63;

    const bool isR = (wid < 4);
    const int  l   = isR ? wid : ((wid == 7) ? 0 : wid - 3);   // layer

    // chunk 0, step 0 reads "previous chunk last step" = hist[l][1][15][*]
    if (isR) hist[wid][1][CHUNK - 1][c] = 0.0f;

    // ---- weights: 192 per lane, register-resident ----
    float w[192] = {};
    float bias0 = 0.f, bias1 = 0.f, bias2 = 0.f;
    if (isR) {
        const float* wb = w_hh + l * (192 * 64);
        #pragma unroll
        for (int i = 0; i < 3; ++i)
            #pragma unroll
            for (int q = 0; q < 16; ++q) {
                const float4 f = *(const float4*)(wb + (i * 64 + c) * 64 + q * 4);
                w[i*64 + q*4 + 0] = f.x; w[i*64 + q*4 + 1] = f.y;
                w[i*64 + q*4 + 2] = f.z; w[i*64 + q*4 + 3] = f.w;
            }
        bias0 = b_hh[l*192 + c]; bias1 = b_hh[l*192 + 64 + c]; bias2 = b_hh[l*192 + 128 + c];
    } else if (wid != 7) {
        const float* wb = w_ih_rest + (l - 1) * (192 * 64);
        #pragma unroll
        for (int i = 0; i < 3; ++i)
            #pragma unroll
            for (int q = 0; q < 16; ++q) {
                const float4 f = *(const float4*)(wb + (i * 64 + c) * 64 + q * 4);
                w[i*64 + q*4 + 0] = f.x; w[i*64 + q*4 + 1] = f.y;
                w[i*64 + q*4 + 2] = f.z; w[i*64 + q*4 + 3] = f.w;
            }
        bias0 = b_ih[l*192 + c]; bias1 = b_ih[l*192 + 64 + c]; bias2 = b_ih[l*192 + 128 + c];
    } else {
        #pragma unroll
        for (int i = 0; i < 3; ++i) {
            const float4 f = *(const float4*)(w_ih0 + (i * 64 + c) * 4);
            w[i*4 + 0] = f.x; w[i*4 + 1] = f.y; w[i*4 + 2] = f.z; w[i*4 + 3] = f.w;
        }
        bias0 = b_ih[c]; bias1 = b_ih[64 + c]; bias2 = b_ih[128 + c];
    }
    // pin: asm defs are not rematerializable -> no in-loop weight reloads
    #pragma unroll
    for (int i = 0; i < 192; ++i) asm volatile("" : "+v"(w[i]));

    const float* xbase = x + (size_t)b * (T_LEN * 4);
    float hc = 0.0f;                       // R: this lane's h value

    __syncthreads();

    // ---- phase loop ----
    for (int p = -1; p <= 2 * 3 + NCHUNK - 1; ++p) {   // -1 .. 133
        if (isR) {
            const int k = p - 2 * l;
            if (0 <= k && k < NCHUNK) {
                const int buf = k & 1;
                for (int j = 0; j < CHUNK; ++j) {
                    const float4* hv = (j == 0) ? (const float4*)hist[l][buf ^ 1][CHUNK - 1]
                                                : (const float4*)hist[l][buf][j - 1];
                    float a0 = bias0, a1 = bias1, a2 = bias2;
                    #pragma unroll
                    for (int q = 0; q < 16; ++q) {
                        const float4 f = hv[q];
                        a0 = fmaf(f.x, w[      q*4+0], a0); a0 = fmaf(f.y, w[      q*4+1], a0);
                        a0 = fmaf(f.z, w[      q*4+2], a0); a0 = fmaf(f.w, w[      q*4+3], a0);
                        a1 = fmaf(f.x, w[ 64 + q*4+0], a1); a1 = fmaf(f.y, w[ 64 + q*4+1], a1);
                        a1 = fmaf(f.z, w[ 64 + q*4+2], a1); a1 = fmaf(f.w, w[ 64 + q*4+3], a1);
                        a2 = fmaf(f.x, w[128 + q*4+0], a2); a2 = fmaf(f.y, w[128 + q*4+1], a2);
                        a2 = fmaf(f.z, w[128 + q*4+2], a2); a2 = fmaf(f.w, w[128 + q*4+3], a2);
                    }
                    const float xr = gxb[l][buf][j][c];
                    const float xz = gxb[l][buf][j][64 + c];
                    const float xn = gxb[l][buf][j][128 + c];
                    const float rr = 1.0f / (1.0f + __expf(-(xr + a0)));
                    const float zz = 1.0f / (1.0f + __expf(-(xz + a1)));
                    const float e  = __expf(2.0f * (xn + rr * a2));
                    const float nn = 1.0f - 2.0f / (e + 1.0f);     // tanh
                    hc = nn + zz * (hc - nn);                      // (1-z)n + z h
                    hist[l][buf][j][c] = hc;
                }
            }
        } else {
            const int cg = p - 2 * l + 1;
            if (0 <= cg && cg < NCHUNK) {
                const int buf = cg & 1;
                if (wid != 7) {
                    for (int j = 0; j < CHUNK; ++j) {
                        const float4* hv = (const float4*)hist[l - 1][buf][j];
                        float a0 = bias0, a1 = bias1, a2 = bias2;
                        #pragma unroll
                        for (int q = 0; q < 16; ++q) {
                            const float4 f = hv[q];
                            a0 = fmaf(f.x, w[      q*4+0], a0); a0 = fmaf(f.y, w[      q*4+1], a0);
                            a0 = fmaf(f.z, w[      q*4+2], a0); a0 = fmaf(f.w, w[      q*4+3], a0);
                            a1 = fmaf(f.x, w[ 64 + q*4+0], a1); a1 = fmaf(f.y, w[ 64 + q*4+1], a1);
                            a1 = fmaf(f.z, w[ 64 + q*4+2], a1); a1 = fmaf(f.w, w[ 64 + q*4+3], a1);
                            a2 = fmaf(f.x, w[128 + q*4+0], a2); a2 = fmaf(f.y, w[128 + q*4+1], a2);
                            a2 = fmaf(f.z, w[128 + q*4+2], a2); a2 = fmaf(f.w, w[128 + q*4+3], a2);
                        }
                        gxb[l][buf][j][c]       = a0;
                        gxb[l][buf][j][64 + c]  = a1;
                        gxb[l][buf][j][128 + c] = a2;
                    }
                } else {
                    for (int j = 0; j < CHUNK; ++j) {
                        const float4 xv = *(const float4*)(xbase + (cg * CHUNK + j) * 4);
                        float a0 = bias0 + xv.x*w[0] + xv.y*w[1]  + xv.z*w[2]  + xv.w*w[3];
                        float a1 = bias1 + xv.x*w[4] + xv.y*w[5]  + xv.z*w[6]  + xv.w*w[7];
                        float a2 = bias2 + xv.x*w[8] + xv.y*w[9]  + xv.z*w[10] + xv.w*w[11];
                        gxb[0][buf][j][c]       = a0;
                        gxb[0][buf][j][64 + c]  = a1;
                        gxb[0][buf][j][128 + c] = a2;
                    }
                }
            }
        }
        __syncthreads();
    }

    // ---- fused FC head on layer-3 final h (chunk 127 -> buf 1, j 15) ----
    if (tid < 5) {
        float acc = fc_b[tid];
        const float* wf = fc_w + tid * 64;
        #pragma unroll
        for (int k = 0; k < 64; ++k) acc = fmaf(hist[3][1][CHUNK - 1][k], wf[k], acc);
        out[(size_t)b * 5 + tid] = acc;
    }
}

extern "C" void kernel_launch(void* const* d_in, const int* in_sizes, int n_in,
                              void* d_out, int out_size, void* d_ws, size_t ws_size,
                              hipStream_t stream) {
    const float* x         = (const float*)d_in[0];
    const float* w_ih0     = (const float*)d_in[1];
    const float* w_ih_rest = (const float*)d_in[2];
    const float* w_hh      = (const float*)d_in[3];
    const float* b_ih      = (const float*)d_in[4];
    const float* b_hh      = (const float*)d_in[5];
    const float* fc_w      = (const float*)d_in[6];
    const float* fc_b      = (const float*)d_in[7];

    gru_fused<<<dim3(256), dim3(NTHREADS), 0, stream>>>(
        x, w_ih0, w_ih_rest, w_hh, b_ih, b_hh, fc_w, fc_b, (float*)d_out);
}

// Round 9
// 24654.057 us; speedup vs baseline: 1.5038x; 1.5038x over previous
//
#include <hip/hip_runtime.h>

#define T_LEN   2048
#define CHUNK   16
#define NCHUNK  (T_LEN / CHUNK)   // 128
#define NTHREADS 512              // 8 waves

// Barrier-light chunked GRU. Block b = batch row b. 8 waves:
//   waves 0-3 ("R"): layer l = wid. Lane c owns W_hh rows {c,64+c,128+c}
//     (192 f32 = 48 float4 in regs). Runs CHUNK recurrence steps privately
//     per phase; h broadcast via wave-local LDS history; gate combine
//     in-lane (lane c's 3 dots ARE gate c's hr/hz/hn).
//   waves 4-6: gx projections for layers 1-3; wave 7: layer-0 gx from x.
// Phase p: R-wave l does chunk p-2l; G-wave for layer j does chunk p-2j+1.
// ONE __syncthreads per phase (134 total).
//
// Register strategy (r8 post-mortem): __launch_bounds__(512, 1) = "min 1
// wave/EU" -- the m214 attn kernels reach 249 VGPR/0 spill at 512 threads
// on this toolchain, so the 256 budget is reachable; r8's waves_per_eu(2,2)
// clamped it to 128. NO asm pins this time: if the budget still comes back
// 128, the allocator falls back to L2-rematerialization (~2.3 ms graceful)
// instead of r8's 37 ms scratch-spill catastrophe.
__global__ __launch_bounds__(NTHREADS, 1)
void gru_fused(const float* __restrict__ x,
               const float* __restrict__ w_ih0,
               const float* __restrict__ w_ih_rest,
               const float* __restrict__ w_hh,
               const float* __restrict__ b_ih,
               const float* __restrict__ b_hh,
               const float* __restrict__ fc_w,
               const float* __restrict__ fc_b,
               float* __restrict__ out)
{
    __shared__ __align__(16) float hist[4][2][CHUNK][64];    // 32 KB  h history
    __shared__ __align__(16) float gxb [4][2][CHUNK][192];   // 96 KB  gx results

    const int tid = threadIdx.x;
    const int b   = blockIdx.x;
    const int wid = tid >> 6;
    const int c   = tid & 63;

    const bool isR = (wid < 4);
    const int  l   = isR ? wid : ((wid == 7) ? 0 : wid - 3);   // layer

    // chunk 0, step 0 reads "previous chunk last step" = hist[l][1][15][*]
    if (isR) hist[wid][1][CHUNK - 1][c] = 0.0f;

    // ---- weights: 48 float4 per lane, compile-time-indexed only ----
    float4 w4[48];
    float bias0, bias1, bias2;
    if (isR) {
        const float* wb = w_hh + l * (192 * 64);
        #pragma unroll
        for (int i = 0; i < 3; ++i)
            #pragma unroll
            for (int q = 0; q < 16; ++q)
                w4[i * 16 + q] = *(const float4*)(wb + (i * 64 + c) * 64 + q * 4);
        bias0 = b_hh[l*192 + c]; bias1 = b_hh[l*192 + 64 + c]; bias2 = b_hh[l*192 + 128 + c];
    } else if (wid != 7) {
        const float* wb = w_ih_rest + (l - 1) * (192 * 64);
        #pragma unroll
        for (int i = 0; i < 3; ++i)
            #pragma unroll
            for (int q = 0; q < 16; ++q)
                w4[i * 16 + q] = *(const float4*)(wb + (i * 64 + c) * 64 + q * 4);
        bias0 = b_ih[l*192 + c]; bias1 = b_ih[l*192 + 64 + c]; bias2 = b_ih[l*192 + 128 + c];
    } else {
        #pragma unroll
        for (int i = 0; i < 3; ++i)
            w4[i] = *(const float4*)(w_ih0 + (i * 64 + c) * 4);
        bias0 = b_ih[c]; bias1 = b_ih[64 + c]; bias2 = b_ih[128 + c];
    }

    const float* xbase = x + (size_t)b * (T_LEN * 4);
    float hc = 0.0f;                       // R: this lane's h value

    __syncthreads();

    // ---- phase loop ----
    for (int p = -1; p <= 2 * 3 + NCHUNK - 1; ++p) {   // -1 .. 133
        if (isR) {
            const int k = p - 2 * l;
            if (0 <= k && k < NCHUNK) {
                const int buf = k & 1;
                for (int j = 0; j < CHUNK; ++j) {
                    const float4* hv = (j == 0) ? (const float4*)hist[l][buf ^ 1][CHUNK - 1]
                                                : (const float4*)hist[l][buf][j - 1];
                    // 6 independent 32-FMA chains (issue-bound, not latency-bound)
                    float a0 = bias0, a1 = bias1, a2 = bias2;
                    float b0 = 0.f,  b1 = 0.f,  b2 = 0.f;
                    #pragma unroll
                    for (int q = 0; q < 8; ++q) {
                        const float4 f = hv[q];
                        a0 = fmaf(f.x, w4[     q].x, a0); a0 = fmaf(f.y, w4[     q].y, a0);
                        a0 = fmaf(f.z, w4[     q].z, a0); a0 = fmaf(f.w, w4[     q].w, a0);
                        a1 = fmaf(f.x, w4[16 + q].x, a1); a1 = fmaf(f.y, w4[16 + q].y, a1);
                        a1 = fmaf(f.z, w4[16 + q].z, a1); a1 = fmaf(f.w, w4[16 + q].w, a1);
                        a2 = fmaf(f.x, w4[32 + q].x, a2); a2 = fmaf(f.y, w4[32 + q].y, a2);
                        a2 = fmaf(f.z, w4[32 + q].z, a2); a2 = fmaf(f.w, w4[32 + q].w, a2);
                    }
                    #pragma unroll
                    for (int q = 8; q < 16; ++q) {
                        const float4 f = hv[q];
                        b0 = fmaf(f.x, w4[     q].x, b0); b0 = fmaf(f.y, w4[     q].y, b0);
                        b0 = fmaf(f.z, w4[     q].z, b0); b0 = fmaf(f.w, w4[     q].w, b0);
                        b1 = fmaf(f.x, w4[16 + q].x, b1); b1 = fmaf(f.y, w4[16 + q].y, b1);
                        b1 = fmaf(f.z, w4[16 + q].z, b1); b1 = fmaf(f.w, w4[16 + q].w, b1);
                        b2 = fmaf(f.x, w4[32 + q].x, b2); b2 = fmaf(f.y, w4[32 + q].y, b2);
                        b2 = fmaf(f.z, w4[32 + q].z, b2); b2 = fmaf(f.w, w4[32 + q].w, b2);
                    }
                    const float hr = a0 + b0, hz = a1 + b1, hn = a2 + b2;
                    const float xr = gxb[l][buf][j][c];
                    const float xz = gxb[l][buf][j][64 + c];
                    const float xn = gxb[l][buf][j][128 + c];
                    const float rr = 1.0f / (1.0f + __expf(-(xr + hr)));
                    const float zz = 1.0f / (1.0f + __expf(-(xz + hz)));
                    const float e  = __expf(2.0f * (xn + rr * hn));
                    const float nn = 1.0f - 2.0f / (e + 1.0f);     // tanh
                    hc = nn + zz * (hc - nn);                      // (1-z)n + z h
                    hist[l][buf][j][c] = hc;
                }
            }
        } else {
            const int cg = p - 2 * l + 1;
            if (0 <= cg && cg < NCHUNK) {
                const int buf = cg & 1;
                if (wid != 7) {
                    for (int j = 0; j < CHUNK; ++j) {
                        const float4* hv = (const float4*)hist[l - 1][buf][j];
                        float a0 = bias0, a1 = bias1, a2 = bias2;
                        float b0 = 0.f,  b1 = 0.f,  b2 = 0.f;
                        #pragma unroll
                        for (int q = 0; q < 8; ++q) {
                            const float4 f = hv[q];
                            a0 = fmaf(f.x, w4[     q].x, a0); a0 = fmaf(f.y, w4[     q].y, a0);
                            a0 = fmaf(f.z, w4[     q].z, a0); a0 = fmaf(f.w, w4[     q].w, a0);
                            a1 = fmaf(f.x, w4[16 + q].x, a1); a1 = fmaf(f.y, w4[16 + q].y, a1);
                            a1 = fmaf(f.z, w4[16 + q].z, a1); a1 = fmaf(f.w, w4[16 + q].w, a1);
                            a2 = fmaf(f.x, w4[32 + q].x, a2); a2 = fmaf(f.y, w4[32 + q].y, a2);
                            a2 = fmaf(f.z, w4[32 + q].z, a2); a2 = fmaf(f.w, w4[32 + q].w, a2);
                        }
                        #pragma unroll
                        for (int q = 8; q < 16; ++q) {
                            const float4 f = hv[q];
                            b0 = fmaf(f.x, w4[     q].x, b0); b0 = fmaf(f.y, w4[     q].y, b0);
                            b0 = fmaf(f.z, w4[     q].z, b0); b0 = fmaf(f.w, w4[     q].w, b0);
                            b1 = fmaf(f.x, w4[16 + q].x, b1); b1 = fmaf(f.y, w4[16 + q].y, b1);
                            b1 = fmaf(f.z, w4[16 + q].z, b1); b1 = fmaf(f.w, w4[16 + q].w, b1);
                            b2 = fmaf(f.x, w4[32 + q].x, b2); b2 = fmaf(f.y, w4[32 + q].y, b2);
                            b2 = fmaf(f.z, w4[32 + q].z, b2); b2 = fmaf(f.w, w4[32 + q].w, b2);
                        }
                        gxb[l][buf][j][c]       = a0 + b0;
                        gxb[l][buf][j][64 + c]  = a1 + b1;
                        gxb[l][buf][j][128 + c] = a2 + b2;
                    }
                } else {
                    for (int j = 0; j < CHUNK; ++j) {
                        const float4 xv = *(const float4*)(xbase + (cg * CHUNK + j) * 4);
                        gxb[0][buf][j][c]       = bias0 + xv.x*w4[0].x + xv.y*w4[0].y + xv.z*w4[0].z + xv.w*w4[0].w;
                        gxb[0][buf][j][64 + c]  = bias1 + xv.x*w4[1].x + xv.y*w4[1].y + xv.z*w4[1].z + xv.w*w4[1].w;
                        gxb[0][buf][j][128 + c] = bias2 + xv.x*w4[2].x + xv.y*w4[2].y + xv.z*w4[2].z + xv.w*w4[2].w;
                    }
                }
            }
        }
        __syncthreads();
    }

    // ---- fused FC head on layer-3 final h (chunk 127 -> buf 1, j 15) ----
    if (tid < 5) {
        float acc = fc_b[tid];
        const float* wf = fc_w + tid * 64;
        #pragma unroll
        for (int k = 0; k < 64; ++k) acc = fmaf(hist[3][1][CHUNK - 1][k], wf[k], acc);
        out[(size_t)b * 5 + tid] = acc;
    }
}

extern "C" void kernel_launch(void* const* d_in, const int* in_sizes, int n_in,
                              void* d_out, int out_size, void* d_ws, size_t ws_size,
                              hipStream_t stream) {
    const float* x         = (const float*)d_in[0];
    const float* w_ih0     = (const float*)d_in[1];
    const float* w_ih_rest = (const float*)d_in[2];
    const float* w_hh      = (const float*)d_in[3];
    const float* b_ih      = (const float*)d_in[4];
    const float* b_hh      = (const float*)d_in[5];
    const float* fc_w      = (const float*)d_in[6];
    const float* fc_b      = (const float*)d_in[7];

    gru_fused<<<dim3(256), dim3(NTHREADS), 0, stream>>>(
        x, w_ih0, w_ih_rest, w_hh, b_ih, b_hh, fc_w, fc_b, (float*)d_out);
}

// Round 10
// 3492.354 us; speedup vs baseline: 10.6157x; 7.0594x over previous
//
#include <hip/hip_runtime.h>

#define T_LEN    2048
#define CHUNK    16
#define NCHUNK   128
#define NTHREADS 512   // 8 waves

// Fused 4-layer GRU, fp32, diagonal chunk pipeline + per-step barriers.
// Block b = batch row b (256 blocks, 1/CU via 128KB LDS).
//
// R (recurrence, all 8 waves): wave w=(l,sub): layer l=w>>1, gates
//   [32*sub,32*sub+32). Lane pair (2i,2i+1) splits gate i's three W_hh
//   rows by k-half -> 96 resident weight floats/lane (fits the MEASURED
//   128-VGPR budget at 512 threads; 192/lane designs spill - r8/r9).
//   Per step: 96 FMA + shfl_xor(1) reduce; even lane does the gate math.
//   Cross-sub h dependency -> one __syncthreads per step.
// G (input projections, same waves, interleaved between barriers):
//   r8's diagonal schedule: phase p, layer lg computes gx for chunk
//   cg=p-2lg+1 from hist[lg-1] (written last phase, opposite parity).
//   Weights STREAMED from L2 once per phase (147KB/phase = 9KB/step vs
//   344KB/step in r1-r7) in 8-float segments; partials accumulated into
//   gxb in LDS (no persistent accs, no atomics). 576 ih rows: wave w owns
//   rows [64w,64w+64) (seg s at even step j=2s); leftover rows 512-575
//   seg-sliced across waves at odd j=2w+1 (barrier-ordered, deterministic).
//   Layer-0 gx (4-wide) by waves 4-6 at j==3.
__global__ __launch_bounds__(NTHREADS, 1)
void gru_fused(const float* __restrict__ x,
               const float* __restrict__ w_ih0,
               const float* __restrict__ w_ih_rest,
               const float* __restrict__ w_hh,
               const float* __restrict__ b_ih,
               const float* __restrict__ b_hh,
               const float* __restrict__ fc_w,
               const float* __restrict__ fc_b,
               float* __restrict__ out)
{
    __shared__ __align__(16) float hist[4][2][CHUNK][64];    // 32 KB
    __shared__ __align__(16) float gxb [4][2][CHUNK][192];   // 96 KB

    const int tid = threadIdx.x;
    const int b   = blockIdx.x;
    const int w   = tid >> 6;        // wave 0..7
    const int c   = tid & 63;        // lane

    // ---- R identity ----
    const int l   = w >> 1;          // layer 0..3
    const int sub = w & 1;
    const int pr  = c >> 1;          // gate-pair index 0..31
    const int hh  = c & 1;           // k-half
    const int gg  = sub * 32 + pr;   // gate 0..63

    // R weights: k-half hh of rows {gg,64+gg,128+gg} of W_hh[l] = 24 float4
    float4 wr[24];
    {
        const float* base = w_hh + l * 12288;
        #pragma unroll
        for (int i = 0; i < 3; ++i)
            #pragma unroll
            for (int q = 0; q < 8; ++q)
                wr[i * 8 + q] = *(const float4*)(base + (i * 64 + gg) * 64 + hh * 32 + q * 4);
    }
    // gate biases (used by even lane in combine)
    const float bhr = b_hh[l * 192 +       gg];
    const float bhz = b_hh[l * 192 +  64 + gg];
    const float bhn = b_hh[l * 192 + 128 + gg];

    // ---- G identity: own block row fr = 64w + c (layers 1..3) ----
    const int   fr   = 64 * w + c;          // 0..511
    const int   lgw  = fr / 192 + 1;        // 1..3
    const int   rG   = fr % 192;
    const float biasG = b_ih[lgw * 192 + rG];
    const float* wG   = w_ih_rest + (lgw - 1) * 12288 + rG * 64;

    // block8: rows 512..575 (layer 3, local 128+c), this wave does seg w
    const float* wG8   = w_ih_rest + 2 * 12288 + (128 + c) * 64 + w * 8;
    const float biasG8 = b_ih[3 * 192 + 128 + c];   // only wave 0 uses

    // layer-0 duty: waves 4..6, row r0=(w-4)*64+c, 4-wide
    const int  r0    = (w - 4) * 64 + c;
    const bool hasL0 = (w >= 4 && w <= 6);
    float4 w0v = make_float4(0.f, 0.f, 0.f, 0.f);
    float  b0v = 0.f;
    if (hasL0) { w0v = *(const float4*)(w_ih0 + r0 * 4); b0v = b_ih[r0]; }

    const float* xrow = x + (size_t)b * (T_LEN * 4);

    if (w < 4) hist[w][1][CHUNK - 1][c] = 0.f;   // h0=0 (chunk0 reads buf^1 tail)
    float hc = 0.f;
    __syncthreads();

    for (int p = -1; p <= 133; ++p) {
        const int  kR    = p - 2 * l;            const bool rAct  = (0 <= kR  && kR  < NCHUNK);
        const int  bufR  = kR & 1;
        const int  cgO   = p - 2 * lgw + 1;      const bool gAct  = (0 <= cgO && cgO < NCHUNK);
        const int  bufO  = cgO & 1;
        const int  cg3   = p - 5;                const bool g8Act = (0 <= cg3 && cg3 < NCHUNK);
        const int  buf3  = cg3 & 1;
        const int  cg0   = p + 1;                const bool g0Act = hasL0 && (0 <= cg0 && cg0 < NCHUNK);
        const int  buf0  = cg0 & 1;

        #pragma unroll 1
        for (int j = 0; j < CHUNK; ++j) {
            // ---------- R step ----------
            if (rAct) {
                const float* hv  = (j == 0) ? hist[l][bufR ^ 1][CHUNK - 1]
                                            : hist[l][bufR][j - 1];
                const float* hvh = hv + hh * 32;
                float a0 = 0.f, a1 = 0.f, a2 = 0.f;
                #pragma unroll
                for (int q = 0; q < 8; ++q) {
                    const float4 f = *(const float4*)(hvh + q * 4);
                    a0 = fmaf(f.x, wr[     q].x, a0); a0 = fmaf(f.y, wr[     q].y, a0);
                    a0 = fmaf(f.z, wr[     q].z, a0); a0 = fmaf(f.w, wr[     q].w, a0);
                    a1 = fmaf(f.x, wr[ 8 + q].x, a1); a1 = fmaf(f.y, wr[ 8 + q].y, a1);
                    a1 = fmaf(f.z, wr[ 8 + q].z, a1); a1 = fmaf(f.w, wr[ 8 + q].w, a1);
                    a2 = fmaf(f.x, wr[16 + q].x, a2); a2 = fmaf(f.y, wr[16 + q].y, a2);
                    a2 = fmaf(f.z, wr[16 + q].z, a2); a2 = fmaf(f.w, wr[16 + q].w, a2);
                }
                a0 += __shfl_xor(a0, 1);
                a1 += __shfl_xor(a1, 1);
                a2 += __shfl_xor(a2, 1);
                if (hh == 0) {
                    const float xr = gxb[l][bufR][j][      gg];
                    const float xz = gxb[l][bufR][j][ 64 + gg];
                    const float xn = gxb[l][bufR][j][128 + gg];
                    const float rr = 1.f / (1.f + __expf(-(xr + (a0 + bhr))));
                    const float zz = 1.f / (1.f + __expf(-(xz + (a1 + bhz))));
                    const float e  = __expf(2.f * (xn + rr * (a2 + bhn)));
                    const float nn = 1.f - 2.f / (e + 1.f);       // tanh
                    hc = nn + zz * (hc - nn);                     // (1-z)n + z h
                    hist[l][bufR][j][gg] = hc;
                }
            }
            // ---------- G own block: seg s=j/2 at even j ----------
            if (gAct && (j & 1) == 0) {
                const int s = j >> 1;
                const float4 wa = *(const float4*)(wG + s * 8);
                const float4 wb = *(const float4*)(wG + s * 8 + 4);
                #pragma unroll
                for (int t = 0; t < CHUNK; ++t) {
                    const float* hsrc = hist[lgw - 1][bufO][t] + s * 8;
                    const float4 ha = *(const float4*)(hsrc);
                    const float4 hb = *(const float4*)(hsrc + 4);
                    float d = ha.x * wa.x;
                    d = fmaf(ha.y, wa.y, d); d = fmaf(ha.z, wa.z, d); d = fmaf(ha.w, wa.w, d);
                    d = fmaf(hb.x, wb.x, d); d = fmaf(hb.y, wb.y, d);
                    d = fmaf(hb.z, wb.z, d); d = fmaf(hb.w, wb.w, d);
                    float* dst = &gxb[lgw][bufO][t][rG];
                    *dst = (s == 0) ? (biasG + d) : (*dst + d);
                }
            }
            // ---------- block8 (rows 512-575, layer 3): wave w at j==2w+1 ----------
            if (g8Act && j == 2 * w + 1) {
                const float4 wa = *(const float4*)(wG8);
                const float4 wb = *(const float4*)(wG8 + 4);
                #pragma unroll
                for (int t = 0; t < CHUNK; ++t) {
                    const float* hsrc = hist[2][buf3][t] + w * 8;
                    const float4 ha = *(const float4*)(hsrc);
                    const float4 hb = *(const float4*)(hsrc + 4);
                    float d = ha.x * wa.x;
                    d = fmaf(ha.y, wa.y, d); d = fmaf(ha.z, wa.z, d); d = fmaf(ha.w, wa.w, d);
                    d = fmaf(hb.x, wb.x, d); d = fmaf(hb.y, wb.y, d);
                    d = fmaf(hb.z, wb.z, d); d = fmaf(hb.w, wb.w, d);
                    float* dst = &gxb[3][buf3][t][128 + c];
                    *dst = (w == 0) ? (biasG8 + d) : (*dst + d);
                }
            }
            // ---------- layer-0 gx: waves 4-6 at j==3 ----------
            if (g0Act && j == 3) {
                #pragma unroll
                for (int t = 0; t < CHUNK; ++t) {
                    const float4 xv = *(const float4*)(xrow + (cg0 * CHUNK + t) * 4);
                    float d = xv.x * w0v.x;
                    d = fmaf(xv.y, w0v.y, d); d = fmaf(xv.z, w0v.z, d); d = fmaf(xv.w, w0v.w, d);
                    gxb[0][buf0][t][r0] = b0v + d;
                }
            }
            __syncthreads();
        }
    }

    // ---- fused FC head on layer-3 final h (chunk 127 -> parity 1, j=15) ----
    if (tid < 5) {
        float acc = fc_b[tid];
        const float* wf = fc_w + tid * 64;
        #pragma unroll
        for (int k2 = 0; k2 < 64; ++k2)
            acc = fmaf(hist[3][1][CHUNK - 1][k2], wf[k2], acc);
        out[(size_t)b * 5 + tid] = acc;
    }
}

extern "C" void kernel_launch(void* const* d_in, const int* in_sizes, int n_in,
                              void* d_out, int out_size, void* d_ws, size_t ws_size,
                              hipStream_t stream) {
    const float* x         = (const float*)d_in[0];
    const float* w_ih0     = (const float*)d_in[1];
    const float* w_ih_rest = (const float*)d_in[2];
    const float* w_hh      = (const float*)d_in[3];
    const float* b_ih      = (const float*)d_in[4];
    const float* b_hh      = (const float*)d_in[5];
    const float* fc_w      = (const float*)d_in[6];
    const float* fc_b      = (const float*)d_in[7];

    gru_fused<<<dim3(256), dim3(NTHREADS), 0, stream>>>(
        x, w_ih0, w_ih_rest, w_hh, b_ih, b_hh, fc_w, fc_b, (float*)d_out);
}

// Round 11
// 3490.673 us; speedup vs baseline: 10.6209x; 1.0005x over previous
//
#include <hip/hip_runtime.h>

#define T_LEN    2048
#define CHUNK    16
#define NCHUNK   128
#define NTHREADS 512   // 8 waves

// Fused 4-layer GRU, fp32, diagonal chunk pipeline + per-step barriers.
// Block b = batch row b (256 blocks, 1 block/CU via 134KB LDS).
//
// R: wave w=(l,sub): layer l=w>>1, gates [32*sub,32*sub+32). Lane pair
//   (2i,2i+1) splits gate i's three W_hh rows by k-half -> 96 resident
//   weight floats/lane. Per step: 96 FMA + shfl_xor(1) + combine (even
//   lane). One __syncthreads per step (cross-sub-wave h dependency).
// G: r10's diagonal schedule, weights streamed from L2 once per phase.
//
// Register discipline (r10 post-mortem): allocator caps at 128 VGPR @512thr
// and remats const loads rather than keeping them resident; r10's 88-reg
// choice re-streamed W_hh from L2 every step with vmcnt drained by the
// barrier. Fix: pin ONLY wr[24]+hc (~97 regs) via asm; move ALL other
// per-lane constants (biases, weight ptrs, w0v) to LDS/recompute so peak
// demand ~121 <= 128. Pins are safe exactly because demand fits (r8's
// scratch catastrophe was pins with demand 232 > 128).
__global__ __launch_bounds__(NTHREADS, 1)
void gru_fused(const float* __restrict__ x,
               const float* __restrict__ w_ih0,
               const float* __restrict__ w_ih_rest,
               const float* __restrict__ w_hh,
               const float* __restrict__ b_ih,
               const float* __restrict__ b_hh,
               const float* __restrict__ fc_w,
               const float* __restrict__ fc_b,
               float* __restrict__ out)
{
    __shared__ __align__(16) float hist[4][2][CHUNK][64];    // 32 KB
    __shared__ __align__(16) float gxb [4][2][CHUNK][192];   // 96 KB
    __shared__ __align__(16) float bihs[768];                // 3 KB  b_ih
    __shared__ __align__(16) float bhhs[768];                // 3 KB  b_hh

    const int tid = threadIdx.x;
    const int b   = blockIdx.x;
    const int w   = tid >> 6;        // wave 0..7
    const int c   = tid & 63;        // lane

    // ---- R identity ----
    const int l   = w >> 1;          // layer 0..3
    const int sub = w & 1;
    const int pr  = c >> 1;          // gate-pair index 0..31
    const int hh  = c & 1;           // k-half
    const int gg  = sub * 32 + pr;   // gate 0..63

    // ---- G identity ----
    const int  fr   = 64 * w + c;    // 0..511 (own ih row, layers 1..3)
    const int  lgw  = fr / 192 + 1;  // 1..3
    const int  rG   = fr % 192;
    const int  r0   = (w - 4) * 64 + c;
    const bool hasL0 = (w >= 4 && w <= 6);

    // ---- stage biases to LDS; zero h tail ----
    for (int i = tid; i < 192; i += NTHREADS) {
        ((float4*)bihs)[i] = ((const float4*)b_ih)[i];
        ((float4*)bhhs)[i] = ((const float4*)b_hh)[i];
    }
    if (w < 4) hist[w][1][CHUNK - 1][c] = 0.f;   // chunk0 reads buf^1 tail

    // ---- R weights: k-half hh of rows {gg,64+gg,128+gg} of W_hh[l] ----
    float4 wr[24];
    {
        const float* base = w_hh + l * 12288;
        #pragma unroll
        for (int i = 0; i < 3; ++i)
            #pragma unroll
            for (int q = 0; q < 8; ++q)
                wr[i * 8 + q] = *(const float4*)(base + (i * 64 + gg) * 64 + hh * 32 + q * 4);
    }
    // pin exactly the weight set (demand fits the cap -> no spill possible)
    #pragma unroll
    for (int q = 0; q < 24; ++q)
        asm volatile("" : "+v"(wr[q].x), "+v"(wr[q].y), "+v"(wr[q].z), "+v"(wr[q].w));

    const float* xrow = x + (size_t)b * (T_LEN * 4);
    float hc = 0.f;
    __syncthreads();

    for (int p = -1; p <= 133; ++p) {
        const int  kR    = p - 2 * l;            const bool rAct  = (0 <= kR  && kR  < NCHUNK);
        const int  bufR  = kR & 1;
        const int  cgO   = p - 2 * lgw + 1;      const bool gAct  = (0 <= cgO && cgO < NCHUNK);
        const int  bufO  = cgO & 1;
        const int  cg3   = p - 5;                const bool g8Act = (0 <= cg3 && cg3 < NCHUNK);
        const int  buf3  = cg3 & 1;
        const int  cg0   = p + 1;                const bool g0Act = hasL0 && (0 <= cg0 && cg0 < NCHUNK);
        const int  buf0  = cg0 & 1;

        #pragma unroll 1
        for (int j = 0; j < CHUNK; ++j) {
            // ---------- R step ----------
            if (rAct) {
                const float* hv  = (j == 0) ? hist[l][bufR ^ 1][CHUNK - 1]
                                            : hist[l][bufR][j - 1];
                const float* hvh = hv + hh * 32;
                float a0 = 0.f, a1 = 0.f, a2 = 0.f;
                #pragma unroll
                for (int q = 0; q < 8; ++q) {
                    const float4 f = *(const float4*)(hvh + q * 4);
                    a0 = fmaf(f.x, wr[     q].x, a0); a0 = fmaf(f.y, wr[     q].y, a0);
                    a0 = fmaf(f.z, wr[     q].z, a0); a0 = fmaf(f.w, wr[     q].w, a0);
                    a1 = fmaf(f.x, wr[ 8 + q].x, a1); a1 = fmaf(f.y, wr[ 8 + q].y, a1);
                    a1 = fmaf(f.z, wr[ 8 + q].z, a1); a1 = fmaf(f.w, wr[ 8 + q].w, a1);
                    a2 = fmaf(f.x, wr[16 + q].x, a2); a2 = fmaf(f.y, wr[16 + q].y, a2);
                    a2 = fmaf(f.z, wr[16 + q].z, a2); a2 = fmaf(f.w, wr[16 + q].w, a2);
                }
                a0 += __shfl_xor(a0, 1);
                a1 += __shfl_xor(a1, 1);
                a2 += __shfl_xor(a2, 1);
                if (hh == 0) {
                    const float xr = gxb[l][bufR][j][      gg];
                    const float xz = gxb[l][bufR][j][ 64 + gg];
                    const float xn = gxb[l][bufR][j][128 + gg];
                    const float hr = a0 + bhhs[l * 192 +       gg];
                    const float hz = a1 + bhhs[l * 192 +  64 + gg];
                    const float hn = a2 + bhhs[l * 192 + 128 + gg];
                    const float rr = 1.f / (1.f + __expf(-(xr + hr)));
                    const float zz = 1.f / (1.f + __expf(-(xz + hz)));
                    const float e  = __expf(2.f * (xn + rr * hn));
                    const float nn = 1.f - 2.f / (e + 1.f);       // tanh
                    hc = nn + zz * (hc - nn);                     // (1-z)n + z h
                    hist[l][bufR][j][gg] = hc;
                }
            }
            // ---------- G own block: seg s=j/2 at even j ----------
            if (gAct && (j & 1) == 0) {
                const int s = j >> 1;
                const float* wG = w_ih_rest + (lgw - 1) * 12288 + rG * 64 + s * 8;
                const float4 wa = *(const float4*)(wG);
                const float4 wb = *(const float4*)(wG + 4);
                const float biasG = bihs[lgw * 192 + rG];
                #pragma unroll
                for (int t = 0; t < CHUNK; ++t) {
                    const float* hsrc = hist[lgw - 1][bufO][t] + s * 8;
                    const float4 ha = *(const float4*)(hsrc);
                    const float4 hb = *(const float4*)(hsrc + 4);
                    float d = ha.x * wa.x;
                    d = fmaf(ha.y, wa.y, d); d = fmaf(ha.z, wa.z, d); d = fmaf(ha.w, wa.w, d);
                    d = fmaf(hb.x, wb.x, d); d = fmaf(hb.y, wb.y, d);
                    d = fmaf(hb.z, wb.z, d); d = fmaf(hb.w, wb.w, d);
                    float* dst = &gxb[lgw][bufO][t][rG];
                    *dst = (s == 0) ? (biasG + d) : (*dst + d);
                }
            }
            // ---------- block8 (rows 512-575, layer 3): wave w at j==2w+1 ----------
            if (g8Act && j == 2 * w + 1) {
                const float* wG8 = w_ih_rest + 2 * 12288 + (128 + c) * 64 + w * 8;
                const float4 wa = *(const float4*)(wG8);
                const float4 wb = *(const float4*)(wG8 + 4);
                const float biasG8 = bihs[3 * 192 + 128 + c];
                #pragma unroll
                for (int t = 0; t < CHUNK; ++t) {
                    const float* hsrc = hist[2][buf3][t] + w * 8;
                    const float4 ha = *(const float4*)(hsrc);
                    const float4 hb = *(const float4*)(hsrc + 4);
                    float d = ha.x * wa.x;
                    d = fmaf(ha.y, wa.y, d); d = fmaf(ha.z, wa.z, d); d = fmaf(ha.w, wa.w, d);
                    d = fmaf(hb.x, wb.x, d); d = fmaf(hb.y, wb.y, d);
                    d = fmaf(hb.z, wb.z, d); d = fmaf(hb.w, wb.w, d);
                    float* dst = &gxb[3][buf3][t][128 + c];
                    *dst = (w == 0) ? (biasG8 + d) : (*dst + d);
                }
            }
            // ---------- layer-0 gx: waves 4-6 at j==3 ----------
            if (g0Act && j == 3) {
                const float4 w0v = *(const float4*)(w_ih0 + r0 * 4);
                const float  b0v = bihs[r0];
                #pragma unroll
                for (int t = 0; t < CHUNK; ++t) {
                    const float4 xv = *(const float4*)(xrow + (cg0 * CHUNK + t) * 4);
                    float d = xv.x * w0v.x;
                    d = fmaf(xv.y, w0v.y, d); d = fmaf(xv.z, w0v.z, d); d = fmaf(xv.w, w0v.w, d);
                    gxb[0][buf0][t][r0] = b0v + d;
                }
            }
            __syncthreads();
        }
    }

    // ---- fused FC head on layer-3 final h (chunk 127 -> parity 1, j=15) ----
    if (tid < 5) {
        float acc = fc_b[tid];
        const float* wf = fc_w + tid * 64;
        #pragma unroll
        for (int k2 = 0; k2 < 64; ++k2)
            acc = fmaf(hist[3][1][CHUNK - 1][k2], wf[k2], acc);
        out[(size_t)b * 5 + tid] = acc;
    }
}

extern "C" void kernel_launch(void* const* d_in, const int* in_sizes, int n_in,
                              void* d_out, int out_size, void* d_ws, size_t ws_size,
                              hipStream_t stream) {
    const float* x         = (const float*)d_in[0];
    const float* w_ih0     = (const float*)d_in[1];
    const float* w_ih_rest = (const float*)d_in[2];
    const float* w_hh      = (const float*)d_in[3];
    const float* b_ih      = (const float*)d_in[4];
    const float* b_hh      = (const float*)d_in[5];
    const float* fc_w      = (const float*)d_in[6];
    const float* fc_b      = (const float*)d_in[7];

    gru_fused<<<dim3(256), dim3(NTHREADS), 0, stream>>>(
        x, w_ih0, w_ih_rest, w_hh, b_ih, b_hh, fc_w, fc_b, (float*)d_out);
}